// Round 2
// baseline (281.122 us; speedup 1.0000x reference)
//
#include <hip/hip_runtime.h>
#include <hip/hip_bf16.h>

// LSTM cell, B=4096, IN=1024, H=1024, K = IN+H = 2048. All I/O float32.
// Pass 1 convert_pack: X=concat(input,hx) -> bf16 Xb; W -> bf16 Wp (rows
//   permuted into the 256-wide-gate-tile staging order of pass 2).
// Pass 2 lstm_gemm8: 256x256 tile, BK=64, 512 thr / 8 waves (2x4), 32x32x16
//   MFMA, double-buffered LDS (128 KB), 8-phase schedule with counted
//   s_waitcnt vmcnt(6).
//   R2 fix: NO "memory" clobbers, builtin s_barrier, inline-asm ds_read_b128
//   with offset: immediates -- prevents the compiler from inserting vmcnt(0)
//   drains every phase (which killed R1's pipeline). Manual lgkmcnt(0) +
//   sched_barrier(0) now carries the ds_read->MFMA dependency (rule 18).

typedef __attribute__((ext_vector_type(8))) __bf16 bf16x8;
typedef __attribute__((ext_vector_type(16))) float f32x16;

__device__ __forceinline__ unsigned short f2bf(float f) {
  union { float f; unsigned int u; } v; v.f = f;
  unsigned int u = v.u + 0x7FFF + ((v.u >> 16) & 1);  // round-to-nearest-even
  return (unsigned short)(u >> 16);
}
__device__ __forceinline__ unsigned int pack2(float a, float b) {
  return (unsigned int)f2bf(a) | ((unsigned int)f2bf(b) << 16);
}

__device__ __forceinline__ void gld_lds16(const void* g, void* l) {
  __builtin_amdgcn_global_load_lds(
      (const __attribute__((address_space(1))) unsigned int*)g,
      (__attribute__((address_space(3))) unsigned int*)l, 16, 0, 0);
}

__device__ __forceinline__ float sigmoidf_fast(float x) {
  return 1.0f / (1.0f + __expf(-x));
}
__device__ __forceinline__ float tanhf_fast(float x) {
  return 1.0f - 2.0f / (__expf(2.0f * x) + 1.0f);
}

// ---------------- Pass 1: fp32 -> bf16 conversion + W permutation ----------
// Wp physical row q (within 256-row block nb): q = nb*256 + h*128 + wcp*32 + r32
// holds gate g = h*2 + (r32>>4), hidden = nb*64 + wcp*16 + (r32&15).
__global__ __launch_bounds__(256) void convert_pack(
    const float* __restrict__ xin, const float* __restrict__ hx,
    const float* __restrict__ Wi, const float* __restrict__ Wf,
    const float* __restrict__ Wg, const float* __restrict__ Wo,
    unsigned short* __restrict__ Xb, unsigned short* __restrict__ Wp) {
  const int t = blockIdx.x * 256 + threadIdx.x;
  const float* src;
  unsigned short* dst;
  if (t < (1 << 20)) {
    const int e = t * 8;
    const int row = e >> 11, k = e & 2047;
    src = (k < 1024) ? (xin + (size_t)row * 1024 + k)
                     : (hx + (size_t)row * 1024 + (k - 1024));
    dst = Xb + e;
  } else {
    const int e = (t - (1 << 20)) * 8;
    const int q = e >> 11, k = e & 2047;
    const int nb = q >> 8, rem = q & 255;
    const int h = rem >> 7, wcp = (rem >> 5) & 3, r32 = rem & 31;
    const int gate = h * 2 + (r32 >> 4);
    const int hidden = nb * 64 + wcp * 16 + (r32 & 15);
    const float* W = gate == 0 ? Wi : (gate == 1 ? Wf : (gate == 2 ? Wg : Wo));
    src = W + (size_t)hidden * 2048 + k;
    dst = Wp + e;
  }
  const float4 lo = *(const float4*)src;
  const float4 hi = *(const float4*)(src + 4);
  uint4 p;
  p.x = pack2(lo.x, lo.y);
  p.y = pack2(lo.z, lo.w);
  p.z = pack2(hi.x, hi.y);
  p.w = pack2(hi.z, hi.w);
  *(uint4*)dst = p;
}

// ---------------- Pass 2: 8-phase MFMA GEMM + fused LSTM gating ------------

#define BAR __builtin_amdgcn_s_barrier()
#define LGKM0                                   \
  do {                                          \
    asm volatile("s_waitcnt lgkmcnt(0)");       \
    __builtin_amdgcn_sched_barrier(0);          \
  } while (0)
#define VM6 asm volatile("s_waitcnt vmcnt(6)")
#define VM0 asm volatile("s_waitcnt vmcnt(0)")
#define SP1 __builtin_amdgcn_s_setprio(1)
#define SP0 __builtin_amdgcn_s_setprio(0)

// one swizzled LDS b128 read: per-lane base vaddr + compile-time offset
#define DSR(dst, va, IMM) \
  asm volatile("ds_read_b128 %0, %1 offset:%2" : "=v"(dst) : "v"(va), "n"(IMM))

// read A quadrant QA of buffer BUF into a[][]  (8 x ds_read_b128)
#define RD_A(BUF, QA) do {                              \
  DSR(a[0][0], vA0, (BUF)*32768 + (QA)*16384);          \
  DSR(a[0][1], vA1, (BUF)*32768 + (QA)*16384);          \
  DSR(a[0][2], vA2, (BUF)*32768 + (QA)*16384);          \
  DSR(a[0][3], vA3, (BUF)*32768 + (QA)*16384);          \
  DSR(a[1][0], vA0, (BUF)*32768 + (QA)*16384 + 4096);   \
  DSR(a[1][1], vA1, (BUF)*32768 + (QA)*16384 + 4096);   \
  DSR(a[1][2], vA2, (BUF)*32768 + (QA)*16384 + 4096);   \
  DSR(a[1][3], vA3, (BUF)*32768 + (QA)*16384 + 4096);   \
} while (0)
// read B half N of buffer BUF into BR[]  (4 x ds_read_b128)
#define RD_B(BUF, N, BR) do {                           \
  DSR(BR[0], vB0, (BUF)*32768 + (N)*16384);             \
  DSR(BR[1], vB1, (BUF)*32768 + (N)*16384);             \
  DSR(BR[2], vB2, (BUF)*32768 + (N)*16384);             \
  DSR(BR[3], vB3, (BUF)*32768 + (N)*16384);             \
} while (0)
// 8 MFMAs: quadrant (QA, QB), full K=64 of the tile
#define MM8(QA, QB, BR)                                                       \
  _Pragma("unroll") for (int kk = 0; kk < 4; ++kk) {                          \
    acc[2*(QA)][QB] = __builtin_amdgcn_mfma_f32_32x32x16_bf16(                \
        a[0][kk], BR[kk], acc[2*(QA)][QB], 0, 0, 0);                          \
    acc[2*(QA)+1][QB] = __builtin_amdgcn_mfma_f32_32x32x16_bf16(              \
        a[1][kk], BR[kk], acc[2*(QA)+1][QB], 0, 0, 0);                        \
  }
// stage A half H of tile KT into buffer BUF (2 x global_load_lds 16B)
#define ST_A(BUF, H, KT)                                                      \
  do {                                                                        \
    gld_lds16(aSrc + ((size_t)((H)*64)) * 2048 + (KT)*64,                     \
              aDst + (BUF)*16384 + (H)*8192);                                 \
    gld_lds16(aSrc + ((size_t)((H)*64 + 128)) * 2048 + (KT)*64,               \
              aDst + (BUF)*16384 + (H)*8192 + 4096);                          \
  } while (0)
#define ST_B(BUF, H, KT)                                                      \
  do {                                                                        \
    gld_lds16(bSrc + ((size_t)((H)*128)) * 2048 + (KT)*64,                    \
              bDst + (BUF)*16384 + (H)*8192);                                 \
    gld_lds16(bSrc + ((size_t)((H)*128 + 64)) * 2048 + (KT)*64,               \
              bDst + (BUF)*16384 + (H)*8192 + 4096);                          \
  } while (0)

__global__ __launch_bounds__(512, 2) void lstm_gemm8(
    const unsigned short* __restrict__ Xb, const unsigned short* __restrict__ Wp,
    const float* __restrict__ cx,
    const float* __restrict__ bi, const float* __restrict__ bfv,
    const float* __restrict__ bg, const float* __restrict__ bo,
    float* __restrict__ out) {
  // A: [buf][h][p][r][k]  (h = m-quadrant half; p = wr; r in [0,64); k in [0,64))
  // B: [buf][h][wcp][r32][k]  (h = n half; wcp = wc; r32 in [0,32))
  __shared__ unsigned short As[2][2][2][64][64];  // 64 KB
  __shared__ unsigned short Bs[2][2][4][32][64];  // 64 KB

  const int tid = threadIdx.x;
  const int lane = tid & 63;
  const int wid = tid >> 6;          // 0..7
  const int wr = wid >> 2;           // 0..1  (128-row half)
  const int wc = wid & 3;            // 0..3  (64-col slice)
  const int l31 = lane & 31;
  const int ghi = lane >> 5;         // k-half within fragment
  const int sxor = l31 & 7;

  const int mbase = blockIdx.x * 256;  // batch tile
  const int nb = blockIdx.y;           // 64-hidden-col block

  // ---- staging sources (slot s_phys=tid&7 holds logical slot s^((row)&7)) --
  const int r8 = tid >> 3;                       // 0..63
  const int jsw = (tid & 7) ^ (r8 & 7);
  const unsigned short* aSrc = Xb + (size_t)(mbase + r8) * 2048 + jsw * 8;
  const unsigned short* bSrc =
      Wp + (size_t)(nb * 256 + (tid >> 8) * 32 + (r8 & 31)) * 2048 + jsw * 8;
  unsigned short* aDst = &As[0][0][0][0][0] + tid * 8;
  unsigned short* bDst = &Bs[0][0][0][0][0] + tid * 8;

  // ---- swizzled ds_read base addresses (byte offsets into LDS) ------------
  // read addr = base + sx0 + (kk^sx12)*32 + IMM(BUF,QA/N,mm)
  const unsigned asb = (unsigned)(unsigned long long)(const void*)&As[0][0][0][0][0];
  const unsigned bsb = (unsigned)(unsigned long long)(const void*)&Bs[0][0][0][0][0];
  const unsigned sx0 = (unsigned)((ghi ^ (sxor & 1)) * 16);
  const unsigned sx12 = (unsigned)((sxor >> 1) & 3);
  const unsigned aBase = asb + wr * 8192 + l31 * 128 + sx0;
  const unsigned bBase = bsb + wc * 4096 + l31 * 128 + sx0;
  const unsigned vA0 = aBase + ((0u ^ sx12) << 5);
  const unsigned vA1 = aBase + ((1u ^ sx12) << 5);
  const unsigned vA2 = aBase + ((2u ^ sx12) << 5);
  const unsigned vA3 = aBase + ((3u ^ sx12) << 5);
  const unsigned vB0 = bBase + ((0u ^ sx12) << 5);
  const unsigned vB1 = bBase + ((1u ^ sx12) << 5);
  const unsigned vB2 = bBase + ((2u ^ sx12) << 5);
  const unsigned vB3 = bBase + ((3u ^ sx12) << 5);

  f32x16 acc[4][2] = {};   // [m-frag 0..3][n-frag 0..1], 128 acc regs
  bf16x8 a[2][4], b0[4], b1[4];

  // ---- prologue: tile0 complete (4 half-tiles) + tile1 partial (3) --------
  ST_A(0, 0, 0); ST_B(0, 0, 0); ST_B(0, 1, 0); ST_A(0, 1, 0);
  ST_A(1, 0, 1); ST_B(1, 0, 1); ST_B(1, 1, 1);
  VM6;  // 14 outstanding -> oldest 8 (all of tile0) landed
  BAR;

  // ---- main loop: 15 iters x 2 K-tiles; peeled final iter ------------------
  int kt = 0;
  for (int i = 0; i < 15; ++i, kt += 2) {
    // ph1: compute buf0 q(0,0); stage buf1.A-h1 (tile kt+1)
    RD_A(0, 0); RD_B(0, 0, b0);
    ST_A(1, 1, kt + 1);
    BAR; LGKM0; SP1; MM8(0, 0, b0); SP0; BAR;
    // ph2: q(0,1); stage buf0.A-h0 (tile kt+2)
    RD_B(0, 1, b1);
    ST_A(0, 0, kt + 2);
    BAR; LGKM0; SP1; MM8(0, 1, b1); SP0; BAR;
    // ph3: q(1,1); stage buf0.B-h0
    RD_A(0, 1);
    ST_B(0, 0, kt + 2);
    BAR; LGKM0; SP1; MM8(1, 1, b1); SP0; BAR;
    // ph4: q(1,0); stage buf0.B-h1; counted wait -> tile kt+1 fully landed
    ST_B(0, 1, kt + 2);
    VM6;
    BAR; SP1; MM8(1, 0, b0); SP0; BAR;
    // ph5: compute buf1 q(0,0); stage buf0.A-h1
    RD_A(1, 0); RD_B(1, 0, b0);
    ST_A(0, 1, kt + 2);
    BAR; LGKM0; SP1; MM8(0, 0, b0); SP0; BAR;
    // ph6: q(0,1); stage buf1.A-h0 (tile kt+3)
    RD_B(1, 1, b1);
    ST_A(1, 0, kt + 3);
    BAR; LGKM0; SP1; MM8(0, 1, b1); SP0; BAR;
    // ph7: q(1,1); stage buf1.B-h0
    RD_A(1, 1);
    ST_B(1, 0, kt + 3);
    BAR; LGKM0; SP1; MM8(1, 1, b1); SP0; BAR;
    // ph8: q(1,0); stage buf1.B-h1; counted wait -> tile kt+2 fully landed
    ST_B(1, 1, kt + 3);
    VM6;
    BAR; SP1; MM8(1, 0, b0); SP0; BAR;
  }
  // peeled final iter: tiles 30 (buf0) / 31 (buf1); only ph1 stages
  RD_A(0, 0); RD_B(0, 0, b0);
  ST_A(1, 1, 31);
  BAR; LGKM0; SP1; MM8(0, 0, b0); SP0; BAR;
  RD_B(0, 1, b1);
  BAR; LGKM0; SP1; MM8(0, 1, b1); SP0; BAR;
  RD_A(0, 1);
  BAR; LGKM0; SP1; MM8(1, 1, b1); SP0; BAR;
  VM0;  // drain: tile31's A-h1 must be in LDS
  BAR; SP1; MM8(1, 0, b0); SP0; BAR;
  RD_A(1, 0); RD_B(1, 0, b0);
  BAR; LGKM0; SP1; MM8(0, 0, b0); SP0; BAR;
  RD_B(1, 1, b1);
  BAR; LGKM0; SP1; MM8(0, 1, b1); SP0; BAR;
  RD_A(1, 1);
  BAR; LGKM0; SP1; MM8(1, 1, b1); SP0;
  SP1; MM8(1, 0, b0); SP0;

  // ---- fused LSTM epilogue (proven 32x32 C-layout + shfl_xor(16)) ----------
  // col c = wc*64 + n*32 + l31 -> gate = n*2 + (l31>>4), hidden = nb*64+wc*16+l15
  const int p = (l31 >> 4) & 1;  // 0: lane holds (i,g); 1: (f,o)
  const int nh = nb * 64 + wc * 16 + (l31 & 15);
  const float bias0 = p ? bfv[nh] : bi[nh];
  const float bias1 = p ? bo[nh] : bg[nh];

  float* outh = out;
  float* outc = out + (size_t)4096 * 1024;

#pragma unroll
  for (int m = 0; m < 4; ++m) {
#pragma unroll
    for (int r = 0; r < 16; ++r) {
      const int row = mbase + wr * 128 + m * 32 + (r & 3) + 8 * (r >> 2) + 4 * ghi;
      const size_t idx = (size_t)row * 1024 + nh;
      const float own0 = acc[m][0][r] + bias0;
      const float own1 = acc[m][1][r] + bias1;
      const float rcv0 = __shfl_xor(own0, 16);
      const float rcv1 = __shfl_xor(own1, 16);
      const float zi = p ? rcv0 : own0;
      const float zf = p ? own0 : rcv0;
      const float zg = p ? rcv1 : own1;
      const float zo = p ? own1 : rcv1;
      const float it = sigmoidf_fast(zi);
      const float ft = sigmoidf_fast(zf);
      const float gt = tanhf_fast(zg);
      const float ot = sigmoidf_fast(zo);
      const float cv = ft * cx[idx] + it * gt;
      const float hv = ot * tanhf_fast(cv);
      float* dst = p ? (outc + idx) : (outh + idx);
      *dst = p ? cv : hv;
    }
  }
}

// ---------------- Fallback (R2): single fused kernel, no workspace ----------
__global__ __launch_bounds__(256) void lstm_fused_fb(
    const float* __restrict__ xin, const float* __restrict__ hx,
    const float* __restrict__ cx,
    const float* __restrict__ Wi, const float* __restrict__ bi,
    const float* __restrict__ Wf, const float* __restrict__ bfv,
    const float* __restrict__ Wg, const float* __restrict__ bg,
    const float* __restrict__ Wo, const float* __restrict__ bo,
    float* __restrict__ out) {
  typedef __attribute__((ext_vector_type(4))) float f32x4;
  __shared__ unsigned short As[128 * 32];
  __shared__ unsigned short Bs[128 * 32];

  const int tid = threadIdx.x;
  const int lane = tid & 63;
  const int wid = tid >> 6;
  const int wr = wid >> 1, wc = wid & 1;
  const int lane15 = lane & 15, quad = lane >> 4;
  const int mbase = blockIdx.x * 128;
  const int nbase = blockIdx.y * 32;

  const int kofs = (tid & 3) * 8;
  const size_t a_off0 = (size_t)(mbase + (tid >> 2)) * 1024 + kofs;
  const size_t a_off1 = a_off0 + (size_t)64 * 1024;

  auto wsel = [&](int g) { return g == 0 ? Wi : (g == 1 ? Wf : (g == 2 ? Wg : Wo)); };
  const int rb0 = tid >> 2;
  const int rb1 = rb0 + 64;
  const float* bsrc0 =
      wsel((rb0 >> 4) & 3) + (size_t)(nbase + (rb0 >> 6) * 16 + (rb0 & 15)) * 2048 + kofs;
  const float* bsrc1 =
      wsel((rb1 >> 4) & 3) + (size_t)(nbase + (rb1 >> 6) * 16 + (rb1 & 15)) * 2048 + kofs;

  uint4* lA0 = (uint4*)(As + (size_t)tid * 8);
  uint4* lA1 = (uint4*)(As + (size_t)(tid + 256) * 8);
  uint4* lB0 = (uint4*)(Bs + (size_t)tid * 8);
  uint4* lB1 = (uint4*)(Bs + (size_t)(tid + 256) * 8);

  f32x4 acc[4][4] = {};

  for (int kt = 0; kt < 64; ++kt) {
    const int kc = kt * 32;
    const float* abase = (kc < 1024 ? xin : hx) + (kc & 1023);
    const float4 a0lo = *(const float4*)(abase + a_off0);
    const float4 a0hi = *(const float4*)(abase + a_off0 + 4);
    const float4 a1lo = *(const float4*)(abase + a_off1);
    const float4 a1hi = *(const float4*)(abase + a_off1 + 4);
    const float4 b0lo = *(const float4*)(bsrc0 + kc);
    const float4 b0hi = *(const float4*)(bsrc0 + kc + 4);
    const float4 b1lo = *(const float4*)(bsrc1 + kc);
    const float4 b1hi = *(const float4*)(bsrc1 + kc + 4);

    uint4 pa0, pa1, pb0, pb1;
    pa0.x = pack2(a0lo.x, a0lo.y); pa0.y = pack2(a0lo.z, a0lo.w);
    pa0.z = pack2(a0hi.x, a0hi.y); pa0.w = pack2(a0hi.z, a0hi.w);
    pa1.x = pack2(a1lo.x, a1lo.y); pa1.y = pack2(a1lo.z, a1lo.w);
    pa1.z = pack2(a1hi.x, a1hi.y); pa1.w = pack2(a1hi.z, a1hi.w);
    pb0.x = pack2(b0lo.x, b0lo.y); pb0.y = pack2(b0lo.z, b0lo.w);
    pb0.z = pack2(b0hi.x, b0hi.y); pb0.w = pack2(b0hi.z, b0hi.w);
    pb1.x = pack2(b1lo.x, b1lo.y); pb1.y = pack2(b1lo.z, b1lo.w);
    pb1.z = pack2(b1hi.x, b1hi.y); pb1.w = pack2(b1hi.z, b1hi.w);

    __syncthreads();
    *lA0 = pa0; *lA1 = pa1; *lB0 = pb0; *lB1 = pb1;
    __syncthreads();

    bf16x8 aa[4], bb[4];
#pragma unroll
    for (int i = 0; i < 4; ++i)
      aa[i] = *reinterpret_cast<const bf16x8*>(&As[(wr * 64 + i * 16 + lane15) * 32 + quad * 8]);
#pragma unroll
    for (int j = 0; j < 4; ++j)
      bb[j] = *reinterpret_cast<const bf16x8*>(&Bs[(wc * 64 + j * 16 + lane15) * 32 + quad * 8]);
#pragma unroll
    for (int i = 0; i < 4; ++i)
#pragma unroll
      for (int j = 0; j < 4; ++j)
        acc[i][j] = __builtin_amdgcn_mfma_f32_16x16x32_bf16(aa[i], bb[j], acc[i][j], 0, 0, 0);
  }

  const int n = nbase + wc * 16 + lane15;
  const float bias_i = bi[n];
  const float bias_f = bfv[n];
  const float bias_g = bg[n];
  const float bias_o = bo[n];
  float* outh = out;
  float* outc = out + (size_t)4096 * 1024;

#pragma unroll
  for (int i = 0; i < 4; ++i) {
#pragma unroll
    for (int r = 0; r < 4; ++r) {
      const int mb = mbase + wr * 64 + i * 16 + quad * 4 + r;
      const size_t idx = (size_t)mb * 1024 + n;
      const float it = sigmoidf_fast(acc[i][0][r] + bias_i);
      const float ft = sigmoidf_fast(acc[i][1][r] + bias_f);
      const float gt = tanhf_fast(acc[i][2][r] + bias_g);
      const float ot = sigmoidf_fast(acc[i][3][r] + bias_o);
      const float cv = ft * cx[idx] + it * gt;
      const float hv = ot * tanhf_fast(cv);
      outh[idx] = hv;
      outc[idx] = cv;
    }
  }
}

extern "C" void kernel_launch(void* const* d_in, const int* in_sizes, int n_in,
                              void* d_out, int out_size, void* d_ws, size_t ws_size,
                              hipStream_t stream) {
  const float* xin = (const float*)d_in[0];
  const float* hx  = (const float*)d_in[1];
  const float* cx  = (const float*)d_in[2];
  const float* Wi  = (const float*)d_in[3];
  const float* bi  = (const float*)d_in[4];
  const float* Wf  = (const float*)d_in[5];
  const float* bf  = (const float*)d_in[6];
  const float* Wg  = (const float*)d_in[7];
  const float* bg  = (const float*)d_in[8];
  const float* Wo  = (const float*)d_in[9];
  const float* bo  = (const float*)d_in[10];
  float* out = (float*)d_out;

  const size_t need = (size_t)2 * 4096 * 2048 * sizeof(unsigned short);  // 32 MB
  if (ws_size >= need) {
    unsigned short* Xb = (unsigned short*)d_ws;
    unsigned short* Wp = Xb + (size_t)4096 * 2048;
    convert_pack<<<8192, 256, 0, stream>>>(xin, hx, Wi, Wf, Wg, Wo, Xb, Wp);
    dim3 grid(4096 / 256, 1024 / 64);
    lstm_gemm8<<<grid, 512, 0, stream>>>(Xb, Wp, cx, bi, bf, bg, bo, out);
  } else {
    dim3 grid(4096 / 128, 1024 / 32);
    lstm_fused_fb<<<grid, 256, 0, stream>>>(xin, hx, cx, Wi, bi, Wf, bf, Wg, bg, Wo, bo, out);
  }
}

// Round 3
// 214.050 us; speedup vs baseline: 1.3133x; 1.3133x over previous
//
#include <hip/hip_runtime.h>
#include <hip/hip_bf16.h>

// LSTM cell, B=4096, IN=1024, H=1024, K = IN+H = 2048. All I/O float32.
// Pass 1 convert_pack: X=concat(input,hx) -> bf16 Xb; W -> bf16 Wp (rows
//   permuted into the 256-wide-gate-tile staging order of pass 2).
// Pass 2 lstm_gemm8: 256x256 tile, BK=64, 512 thr / 8 waves (2x4), 32x32x16
//   MFMA, double-buffered LDS (128 KB), 8-phase schedule with counted
//   s_waitcnt vmcnt(6) (never 0 in steady state).
//   R3: m201-template hygiene -- C++ swizzled ds_reads (compiler-allocated
//   registers, foldable addresses; R2's inline-asm loads caused ~1KB/thread
//   scratch spills), __builtin_amdgcn_s_barrier(), and CLOBBER-FREE waitcnt
//   asm (R1's "memory" clobbers forced a vmcnt(0) drain every phase).

typedef __attribute__((ext_vector_type(8))) __bf16 bf16x8;
typedef __attribute__((ext_vector_type(16))) float f32x16;

__device__ __forceinline__ unsigned short f2bf(float f) {
  union { float f; unsigned int u; } v; v.f = f;
  unsigned int u = v.u + 0x7FFF + ((v.u >> 16) & 1);  // round-to-nearest-even
  return (unsigned short)(u >> 16);
}
__device__ __forceinline__ unsigned int pack2(float a, float b) {
  return (unsigned int)f2bf(a) | ((unsigned int)f2bf(b) << 16);
}

__device__ __forceinline__ void gld_lds16(const void* g, void* l) {
  __builtin_amdgcn_global_load_lds(
      (const __attribute__((address_space(1))) unsigned int*)g,
      (__attribute__((address_space(3))) unsigned int*)l, 16, 0, 0);
}

__device__ __forceinline__ float sigmoidf_fast(float x) {
  return 1.0f / (1.0f + __expf(-x));
}
__device__ __forceinline__ float tanhf_fast(float x) {
  return 1.0f - 2.0f / (__expf(2.0f * x) + 1.0f);
}

// ---------------- Pass 1: fp32 -> bf16 conversion + W permutation ----------
// Wp physical row q (within 256-row block nb): q = nb*256 + h*128 + wcp*32 + r32
// holds gate g = h*2 + (r32>>4), hidden = nb*64 + wcp*16 + (r32&15).
__global__ __launch_bounds__(256) void convert_pack(
    const float* __restrict__ xin, const float* __restrict__ hx,
    const float* __restrict__ Wi, const float* __restrict__ Wf,
    const float* __restrict__ Wg, const float* __restrict__ Wo,
    unsigned short* __restrict__ Xb, unsigned short* __restrict__ Wp) {
  const int t = blockIdx.x * 256 + threadIdx.x;
  const float* src;
  unsigned short* dst;
  if (t < (1 << 20)) {
    const int e = t * 8;
    const int row = e >> 11, k = e & 2047;
    src = (k < 1024) ? (xin + (size_t)row * 1024 + k)
                     : (hx + (size_t)row * 1024 + (k - 1024));
    dst = Xb + e;
  } else {
    const int e = (t - (1 << 20)) * 8;
    const int q = e >> 11, k = e & 2047;
    const int nb = q >> 8, rem = q & 255;
    const int h = rem >> 7, wcp = (rem >> 5) & 3, r32 = rem & 31;
    const int gate = h * 2 + (r32 >> 4);
    const int hidden = nb * 64 + wcp * 16 + (r32 & 15);
    const float* W = gate == 0 ? Wi : (gate == 1 ? Wf : (gate == 2 ? Wg : Wo));
    src = W + (size_t)hidden * 2048 + k;
    dst = Wp + e;
  }
  const float4 lo = *(const float4*)src;
  const float4 hi = *(const float4*)(src + 4);
  uint4 p;
  p.x = pack2(lo.x, lo.y);
  p.y = pack2(lo.z, lo.w);
  p.z = pack2(hi.x, hi.y);
  p.w = pack2(hi.z, hi.w);
  *(uint4*)dst = p;
}

// ---------------- Pass 2: 8-phase MFMA GEMM + fused LSTM gating ------------

#define BAR __builtin_amdgcn_s_barrier()
#define LGKM0 asm volatile("s_waitcnt lgkmcnt(0)")
#define VM6 asm volatile("s_waitcnt vmcnt(6)")
#define VM0 asm volatile("s_waitcnt vmcnt(0)")
#define SP1 __builtin_amdgcn_s_setprio(1)
#define SP0 __builtin_amdgcn_s_setprio(0)

// read A quadrant QA of buffer BUF into a[][]  (8 x ds_read_b128)
#define RD_A(BUF, QA)                                                         \
  _Pragma("unroll") for (int mm = 0; mm < 2; ++mm)                            \
  _Pragma("unroll") for (int kk = 0; kk < 4; ++kk)                            \
      a[mm][kk] = *(const bf16x8*)(Asb + (BUF)*16384 + (QA)*8192 + arow +     \
                                   mm * 2048 + (((kk * 2 + ghi) ^ sxor) << 3));
// read B half N of buffer BUF into BR[]  (4 x ds_read_b128)
#define RD_B(BUF, N, BR)                                                      \
  _Pragma("unroll") for (int kk = 0; kk < 4; ++kk)                            \
      BR[kk] = *(const bf16x8*)(Bsb + (BUF)*16384 + (N)*8192 + brow +         \
                                (((kk * 2 + ghi) ^ sxor) << 3));
// 8 MFMAs: quadrant (QA, QB), full K=64 of the tile
#define MM8(QA, QB, BR)                                                       \
  _Pragma("unroll") for (int kk = 0; kk < 4; ++kk) {                          \
    acc[2*(QA)][QB] = __builtin_amdgcn_mfma_f32_32x32x16_bf16(                \
        a[0][kk], BR[kk], acc[2*(QA)][QB], 0, 0, 0);                          \
    acc[2*(QA)+1][QB] = __builtin_amdgcn_mfma_f32_32x32x16_bf16(              \
        a[1][kk], BR[kk], acc[2*(QA)+1][QB], 0, 0, 0);                        \
  }
// stage A half H of tile KT into buffer BUF (2 x global_load_lds 16B)
#define ST_A(BUF, H, KT)                                                      \
  do {                                                                        \
    gld_lds16(aSrc + ((size_t)((H)*64)) * 2048 + (KT)*64,                     \
              aDst + (BUF)*16384 + (H)*8192);                                 \
    gld_lds16(aSrc + ((size_t)((H)*64 + 128)) * 2048 + (KT)*64,               \
              aDst + (BUF)*16384 + (H)*8192 + 4096);                          \
  } while (0)
#define ST_B(BUF, H, KT)                                                      \
  do {                                                                        \
    gld_lds16(bSrc + ((size_t)((H)*128)) * 2048 + (KT)*64,                    \
              bDst + (BUF)*16384 + (H)*8192);                                 \
    gld_lds16(bSrc + ((size_t)((H)*128 + 64)) * 2048 + (KT)*64,               \
              bDst + (BUF)*16384 + (H)*8192 + 4096);                         \
  } while (0)

__global__ __launch_bounds__(512, 2) void lstm_gemm8(
    const unsigned short* __restrict__ Xb, const unsigned short* __restrict__ Wp,
    const float* __restrict__ cx,
    const float* __restrict__ bi, const float* __restrict__ bfv,
    const float* __restrict__ bg, const float* __restrict__ bo,
    float* __restrict__ out) {
  // A: [buf][h][p][r][k]  (h = m-quadrant half; p = wr; r in [0,64); k in [0,64))
  // B: [buf][h][wcp][r32][k]  (h = n half; wcp = wc; r32 in [0,32))
  __shared__ unsigned short As[2][2][2][64][64];  // 64 KB
  __shared__ unsigned short Bs[2][2][4][32][64];  // 64 KB

  const int tid = threadIdx.x;
  const int lane = tid & 63;
  const int wid = tid >> 6;          // 0..7
  const int wr = wid >> 2;           // 0..1  (128-row half)
  const int wc = wid & 3;            // 0..3  (64-col slice)
  const int l31 = lane & 31;
  const int ghi = lane >> 5;         // k-half within fragment
  const int sxor = l31 & 7;

  const int mbase = blockIdx.x * 256;  // batch tile
  const int nb = blockIdx.y;           // 64-hidden-col block

  // ---- staging sources (slot s_phys=tid&7 holds logical slot s^((row)&7)) --
  const int r8 = tid >> 3;                       // 0..63
  const int jsw = (tid & 7) ^ (r8 & 7);
  const unsigned short* aSrc = Xb + (size_t)(mbase + r8) * 2048 + jsw * 8;
  const unsigned short* bSrc =
      Wp + (size_t)(nb * 256 + (tid >> 8) * 32 + (r8 & 31)) * 2048 + jsw * 8;
  unsigned short* aDst = &As[0][0][0][0][0] + tid * 8;
  unsigned short* bDst = &Bs[0][0][0][0][0] + tid * 8;

  const unsigned short* Asb = &As[0][0][0][0][0];
  const unsigned short* Bsb = &Bs[0][0][0][0][0];
  const int arow = wr * 4096 + l31 * 64;
  const int brow = wc * 2048 + l31 * 64;

  f32x16 acc[4][2] = {};   // [m-frag 0..3][n-frag 0..1], 128 acc regs
  bf16x8 a[2][4], b0[4], b1[4];

  // ---- prologue: tile0 complete (4 half-tiles) + tile1 partial (3) --------
  ST_A(0, 0, 0); ST_B(0, 0, 0); ST_B(0, 1, 0); ST_A(0, 1, 0);
  ST_A(1, 0, 1); ST_B(1, 0, 1); ST_B(1, 1, 1);
  VM6;  // 14 outstanding -> oldest 8 (all of tile0) landed
  BAR;

  // ---- main loop: 15 iters x 2 K-tiles; peeled final iter ------------------
  int kt = 0;
  for (int i = 0; i < 15; ++i, kt += 2) {
    // ph1: compute buf0 q(0,0); stage buf1.A-h1 (tile kt+1)
    RD_A(0, 0); RD_B(0, 0, b0);
    ST_A(1, 1, kt + 1);
    BAR; LGKM0; SP1; MM8(0, 0, b0); SP0; BAR;
    // ph2: q(0,1); stage buf0.A-h0 (tile kt+2)
    RD_B(0, 1, b1);
    ST_A(0, 0, kt + 2);
    BAR; LGKM0; SP1; MM8(0, 1, b1); SP0; BAR;
    // ph3: q(1,1); stage buf0.B-h0
    RD_A(0, 1);
    ST_B(0, 0, kt + 2);
    BAR; LGKM0; SP1; MM8(1, 1, b1); SP0; BAR;
    // ph4: q(1,0); stage buf0.B-h1; counted wait -> tile kt+1 fully landed
    ST_B(0, 1, kt + 2);
    VM6;
    BAR; SP1; MM8(1, 0, b0); SP0; BAR;
    // ph5: compute buf1 q(0,0); stage buf0.A-h1
    RD_A(1, 0); RD_B(1, 0, b0);
    ST_A(0, 1, kt + 2);
    BAR; LGKM0; SP1; MM8(0, 0, b0); SP0; BAR;
    // ph6: q(0,1); stage buf1.A-h0 (tile kt+3)
    RD_B(1, 1, b1);
    ST_A(1, 0, kt + 3);
    BAR; LGKM0; SP1; MM8(0, 1, b1); SP0; BAR;
    // ph7: q(1,1); stage buf1.B-h0
    RD_A(1, 1);
    ST_B(1, 0, kt + 3);
    BAR; LGKM0; SP1; MM8(1, 1, b1); SP0; BAR;
    // ph8: q(1,0); stage buf1.B-h1; counted wait -> tile kt+2 fully landed
    ST_B(1, 1, kt + 3);
    VM6;
    BAR; SP1; MM8(1, 0, b0); SP0; BAR;
  }
  // peeled final iter: tiles 30 (buf0) / 31 (buf1); only ph1 stages
  RD_A(0, 0); RD_B(0, 0, b0);
  ST_A(1, 1, 31);
  BAR; LGKM0; SP1; MM8(0, 0, b0); SP0; BAR;
  RD_B(0, 1, b1);
  BAR; LGKM0; SP1; MM8(0, 1, b1); SP0; BAR;
  RD_A(0, 1);
  BAR; LGKM0; SP1; MM8(1, 1, b1); SP0; BAR;
  VM0;  // drain: tile31's A-h1 must be in LDS
  BAR; SP1; MM8(1, 0, b0); SP0; BAR;
  RD_A(1, 0); RD_B(1, 0, b0);
  BAR; LGKM0; SP1; MM8(0, 0, b0); SP0; BAR;
  RD_B(1, 1, b1);
  BAR; LGKM0; SP1; MM8(0, 1, b1); SP0; BAR;
  RD_A(1, 1);
  BAR; LGKM0; SP1; MM8(1, 1, b1); SP0;
  SP1; MM8(1, 0, b0); SP0;

  // ---- fused LSTM epilogue (proven 32x32 C-layout + shfl_xor(16)) ----------
  // col c = wc*64 + n*32 + l31 -> gate = n*2 + (l31>>4), hidden = nb*64+wc*16+l15
  const int p = (l31 >> 4) & 1;  // 0: lane holds (i,g); 1: (f,o)
  const int nh = nb * 64 + wc * 16 + (l31 & 15);
  const float bias0 = p ? bfv[nh] : bi[nh];
  const float bias1 = p ? bo[nh] : bg[nh];

  float* outh = out;
  float* outc = out + (size_t)4096 * 1024;

#pragma unroll
  for (int m = 0; m < 4; ++m) {
#pragma unroll
    for (int r = 0; r < 16; ++r) {
      const int row = mbase + wr * 128 + m * 32 + (r & 3) + 8 * (r >> 2) + 4 * ghi;
      const size_t idx = (size_t)row * 1024 + nh;
      const float own0 = acc[m][0][r] + bias0;
      const float own1 = acc[m][1][r] + bias1;
      const float rcv0 = __shfl_xor(own0, 16);
      const float rcv1 = __shfl_xor(own1, 16);
      const float zi = p ? rcv0 : own0;
      const float zf = p ? own0 : rcv0;
      const float zg = p ? rcv1 : own1;
      const float zo = p ? own1 : rcv1;
      const float it = sigmoidf_fast(zi);
      const float ft = sigmoidf_fast(zf);
      const float gt = tanhf_fast(zg);
      const float ot = sigmoidf_fast(zo);
      const float cv = ft * cx[idx] + it * gt;
      const float hv = ot * tanhf_fast(cv);
      float* dst = p ? (outc + idx) : (outh + idx);
      *dst = p ? cv : hv;
    }
  }
}

// ---------------- Fallback (R2): single fused kernel, no workspace ----------
__global__ __launch_bounds__(256) void lstm_fused_fb(
    const float* __restrict__ xin, const float* __restrict__ hx,
    const float* __restrict__ cx,
    const float* __restrict__ Wi, const float* __restrict__ bi,
    const float* __restrict__ Wf, const float* __restrict__ bfv,
    const float* __restrict__ Wg, const float* __restrict__ bg,
    const float* __restrict__ Wo, const float* __restrict__ bo,
    float* __restrict__ out) {
  typedef __attribute__((ext_vector_type(4))) float f32x4;
  __shared__ unsigned short As[128 * 32];
  __shared__ unsigned short Bs[128 * 32];

  const int tid = threadIdx.x;
  const int lane = tid & 63;
  const int wid = tid >> 6;
  const int wr = wid >> 1, wc = wid & 1;
  const int lane15 = lane & 15, quad = lane >> 4;
  const int mbase = blockIdx.x * 128;
  const int nbase = blockIdx.y * 32;

  const int kofs = (tid & 3) * 8;
  const size_t a_off0 = (size_t)(mbase + (tid >> 2)) * 1024 + kofs;
  const size_t a_off1 = a_off0 + (size_t)64 * 1024;

  auto wsel = [&](int g) { return g == 0 ? Wi : (g == 1 ? Wf : (g == 2 ? Wg : Wo)); };
  const int rb0 = tid >> 2;
  const int rb1 = rb0 + 64;
  const float* bsrc0 =
      wsel((rb0 >> 4) & 3) + (size_t)(nbase + (rb0 >> 6) * 16 + (rb0 & 15)) * 2048 + kofs;
  const float* bsrc1 =
      wsel((rb1 >> 4) & 3) + (size_t)(nbase + (rb1 >> 6) * 16 + (rb1 & 15)) * 2048 + kofs;

  uint4* lA0 = (uint4*)(As + (size_t)tid * 8);
  uint4* lA1 = (uint4*)(As + (size_t)(tid + 256) * 8);
  uint4* lB0 = (uint4*)(Bs + (size_t)tid * 8);
  uint4* lB1 = (uint4*)(Bs + (size_t)(tid + 256) * 8);

  f32x4 acc[4][4] = {};

  for (int kt = 0; kt < 64; ++kt) {
    const int kc = kt * 32;
    const float* abase = (kc < 1024 ? xin : hx) + (kc & 1023);
    const float4 a0lo = *(const float4*)(abase + a_off0);
    const float4 a0hi = *(const float4*)(abase + a_off0 + 4);
    const float4 a1lo = *(const float4*)(abase + a_off1);
    const float4 a1hi = *(const float4*)(abase + a_off1 + 4);
    const float4 b0lo = *(const float4*)(bsrc0 + kc);
    const float4 b0hi = *(const float4*)(bsrc0 + kc + 4);
    const float4 b1lo = *(const float4*)(bsrc1 + kc);
    const float4 b1hi = *(const float4*)(bsrc1 + kc + 4);

    uint4 pa0, pa1, pb0, pb1;
    pa0.x = pack2(a0lo.x, a0lo.y); pa0.y = pack2(a0lo.z, a0lo.w);
    pa0.z = pack2(a0hi.x, a0hi.y); pa0.w = pack2(a0hi.z, a0hi.w);
    pa1.x = pack2(a1lo.x, a1lo.y); pa1.y = pack2(a1lo.z, a1lo.w);
    pa1.z = pack2(a1hi.x, a1hi.y); pa1.w = pack2(a1hi.z, a1hi.w);
    pb0.x = pack2(b0lo.x, b0lo.y); pb0.y = pack2(b0lo.z, b0lo.w);
    pb0.z = pack2(b0hi.x, b0hi.y); pb0.w = pack2(b0hi.z, b0hi.w);
    pb1.x = pack2(b1lo.x, b1lo.y); pb1.y = pack2(b1lo.z, b1lo.w);
    pb1.z = pack2(b1hi.x, b1hi.y); pb1.w = pack2(b1hi.z, b1hi.w);

    __syncthreads();
    *lA0 = pa0; *lA1 = pa1; *lB0 = pb0; *lB1 = pb1;
    __syncthreads();

    bf16x8 aa[4], bb[4];
#pragma unroll
    for (int i = 0; i < 4; ++i)
      aa[i] = *reinterpret_cast<const bf16x8*>(&As[(wr * 64 + i * 16 + lane15) * 32 + quad * 8]);
#pragma unroll
    for (int j = 0; j < 4; ++j)
      bb[j] = *reinterpret_cast<const bf16x8*>(&Bs[(wc * 64 + j * 16 + lane15) * 32 + quad * 8]);
#pragma unroll
    for (int i = 0; i < 4; ++i)
#pragma unroll
      for (int j = 0; j < 4; ++j)
        acc[i][j] = __builtin_amdgcn_mfma_f32_16x16x32_bf16(aa[i], bb[j], acc[i][j], 0, 0, 0);
  }

  const int n = nbase + wc * 16 + lane15;
  const float bias_i = bi[n];
  const float bias_f = bfv[n];
  const float bias_g = bg[n];
  const float bias_o = bo[n];
  float* outh = out;
  float* outc = out + (size_t)4096 * 1024;

#pragma unroll
  for (int i = 0; i < 4; ++i) {
#pragma unroll
    for (int r = 0; r < 4; ++r) {
      const int mb = mbase + wr * 64 + i * 16 + quad * 4 + r;
      const size_t idx = (size_t)mb * 1024 + n;
      const float it = sigmoidf_fast(acc[i][0][r] + bias_i);
      const float ft = sigmoidf_fast(acc[i][1][r] + bias_f);
      const float gt = tanhf_fast(acc[i][2][r] + bias_g);
      const float ot = sigmoidf_fast(acc[i][3][r] + bias_o);
      const float cv = ft * cx[idx] + it * gt;
      const float hv = ot * tanhf_fast(cv);
      outh[idx] = hv;
      outc[idx] = cv;
    }
  }
}

extern "C" void kernel_launch(void* const* d_in, const int* in_sizes, int n_in,
                              void* d_out, int out_size, void* d_ws, size_t ws_size,
                              hipStream_t stream) {
  const float* xin = (const float*)d_in[0];
  const float* hx  = (const float*)d_in[1];
  const float* cx  = (const float*)d_in[2];
  const float* Wi  = (const float*)d_in[3];
  const float* bi  = (const float*)d_in[4];
  const float* Wf  = (const float*)d_in[5];
  const float* bf  = (const float*)d_in[6];
  const float* Wg  = (const float*)d_in[7];
  const float* bg  = (const float*)d_in[8];
  const float* Wo  = (const float*)d_in[9];
  const float* bo  = (const float*)d_in[10];
  float* out = (float*)d_out;

  const size_t need = (size_t)2 * 4096 * 2048 * sizeof(unsigned short);  // 32 MB
  if (ws_size >= need) {
    unsigned short* Xb = (unsigned short*)d_ws;
    unsigned short* Wp = Xb + (size_t)4096 * 2048;
    convert_pack<<<8192, 256, 0, stream>>>(xin, hx, Wi, Wf, Wg, Wo, Xb, Wp);
    dim3 grid(4096 / 256, 1024 / 64);
    lstm_gemm8<<<grid, 512, 0, stream>>>(Xb, Wp, cx, bi, bf, bg, bo, out);
  } else {
    dim3 grid(4096 / 128, 1024 / 32);
    lstm_fused_fb<<<grid, 256, 0, stream>>>(xin, hx, cx, Wi, bi, Wf, bf, Wg, bg, Wo, bo, out);
  }
}